// Round 9
// baseline (425.854 us; speedup 1.0000x reference)
//
#include <hip/hip_runtime.h>

namespace {

typedef float f4v __attribute__((ext_vector_type(4)));
typedef float f2v __attribute__((ext_vector_type(2)));
typedef unsigned short ushort_t;

constexpr int MM = 3;
constexpr int BB = 16384;
constexpr int DD = 1024;
constexpr int CC = 100;
constexpr int HH = 2048;             // 2*DD
constexpr int DESIRED = BB / CC;     // 163
constexpr int NB  = BB / 256;        // 64 label blocks

// copysum geometry: sequential stripes x d-slices
constexpr int SS    = 21;            // row stripes
constexpr int CHUNK = 781;           // ceil(BB/SS); last stripe = 764
constexpr int DG    = 8;             // d-slices of 128
constexpr int DSL   = 128;
constexpr int NCPS  = SS * DG * MM;  // 504 blocks, 2/CU (54.7 KB LDS)

// base matvec partition
constexpr int DBS   = 4;
constexpr int NBASE = (HH / 256) * DBS * MM;  // 96
// class-GEMM geometry (W2 read exactly once)
constexpr int KC  = 8, JL = HH / KC;    // 256 j per block
constexpr int DG2 = 4,  DR2 = 256;
constexpr int CSPL = 4, CH = CC / CSPL; // 4x25 class split

// ws byte offsets (total 19.7 MB < proven 23.66 MB)
constexpr size_t WS_COUNTS = 0;          // 128 int
constexpr size_t WS_GEN    = 512;        // 128 int
constexpr size_t WS_OFF    = 1024;       // 128 int
constexpr size_t WS_BHIST  = 4096;       // NB*128 int (32 KB)
constexpr size_t WS_BPART  = 36864;      // DBS*MM*HH f32 (96 KB)
constexpr size_t WS_SCSUM  = 135168;     // SS*DG*MM*128 f32 (258 KB)
constexpr size_t WS_ACT    = 393216;     // MM*HH*CC f32 (2.4 MB)
constexpr size_t WS_PSUM   = 2850816;    // SS*MM*CC*DD bf16 (12.9 MB)
constexpr size_t WS_GPART  = 15753216;   // MM*DG2*KC*CC*DR2 bf16 (4.9 MB)

__device__ __forceinline__ float bf2f(ushort_t u) {
  union { unsigned i; float f; } x; x.i = ((unsigned)u) << 16; return x.f;
}
__device__ __forceinline__ ushort_t f2bf(float f) {
  union { float f; unsigned i; } x; x.f = f;
  unsigned r = x.i + 0x7FFFu + ((x.i >> 16) & 1u);
  return (ushort_t)(r >> 16);
}
__device__ __forceinline__ unsigned pack2bf(float a, float b) {
  return (unsigned)f2bf(a) | ((unsigned)f2bf(b) << 16);
}

// L1: per-block label histogram + head labels || base matvec partials.
__global__ void __launch_bounds__(256)
k_hist_base(const int* __restrict__ labels, const float* __restrict__ fused,
            const float* __restrict__ W1, int* __restrict__ bhist,
            float* __restrict__ bpart, float* __restrict__ out_lab) {
  int bid = blockIdx.x, t = threadIdx.x;
  if (bid < NB) {
    __shared__ int h[128];
    if (t < 128) h[t] = 0;
    __syncthreads();
    int b = bid * 256 + t;
    int l = labels[b];
    atomicAdd(&h[l], 1);
    out_lab[b] = (float)l;
    __syncthreads();
    if (t < 128) bhist[bid * 128 + t] = h[t];
  } else {
    int b3 = bid - NB;
    int jb = b3 % (HH / 256), db = (b3 / (HH / 256)) % DBS,
        m = b3 / ((HH / 256) * DBS);
    int j = jb * 256 + t;
    const float* w = W1 + ((size_t)m * (DD + CC)) * HH + j;
    float acc = 0.f;
    int dlo = db * (DD / DBS);
#pragma unroll 8
    for (int d = dlo; d < dlo + DD / DBS; ++d)
      acc = fmaf(fused[d], w[(size_t)d * HH], acc);
    bpart[((size_t)db * MM + m) * HH + j] = acc;
  }
}

// L2: block 0 = plan (counts/gen/off, tail labels, loss);
//     blocks 1..300 = LN-activation -> act[m][j][c].
__global__ void __launch_bounds__(256)
k_plan_act(const int* __restrict__ bhist, const float* __restrict__ W1,
           const float* __restrict__ b1, const float* __restrict__ lng,
           const float* __restrict__ lnb, const float* __restrict__ bpart,
           int* __restrict__ counts, int* __restrict__ gen,
           int* __restrict__ off, float* __restrict__ act,
           float* __restrict__ out_lab_tail, float* __restrict__ out_loss,
           const float* __restrict__ dw, int N) {
  __shared__ float r1[256], r2[256];
  int bid = blockIdx.x, t = threadIdx.x;
  if (bid == 0) {
    __shared__ int s[128], soff[CC + 1];
    int run = 0;
    if (t < 128) {
      for (int blk = 0; blk < NB; ++blk) run += bhist[blk * 128 + t];
      counts[t] = run;
    }
    int cnt = (t < CC) ? run : 0;
    int g = (t < CC && cnt > 0) ? max(DESIRED - cnt, 0) : 0;
    if (t < 128) s[t] = g;
    __syncthreads();
    for (int o = 1; o < 128; o <<= 1) {
      int v = (t < 128 && t >= o) ? s[t - o] : 0;
      __syncthreads();
      if (t < 128) s[t] += v;
      __syncthreads();
    }
    if (t < CC) {
      int excl = s[t] - g;
      gen[t] = g;
      off[t] = excl;
      soff[t] = excl;
    }
    if (t == 0) {
      soff[CC] = N;
      *out_loss = (N > 0) ? 0.1f * dw[0] : 0.0f;
    }
    __syncthreads();
    for (int i = t; i < N; i += 256) {
      int lo = 0, hi = CC;
      while (hi - lo > 1) {
        int mid = (lo + hi) >> 1;
        if (soff[mid] <= i) lo = mid; else hi = mid;
      }
      out_lab_tail[i] = (float)lo;
    }
  } else {
    int b2 = bid - 1;
    int c = b2 % CC, m = b2 / CC;
    const float* w1row = W1 + ((size_t)m * (DD + CC) + DD + c) * HH;
    float h[8];
    float s = 0.f, s2 = 0.f;
#pragma unroll
    for (int k = 0; k < 8; ++k) {
      int j = t + k * 256;
      float base = bpart[(size_t)(0 * MM + m) * HH + j]
                 + bpart[(size_t)(1 * MM + m) * HH + j]
                 + bpart[(size_t)(2 * MM + m) * HH + j]
                 + bpart[(size_t)(3 * MM + m) * HH + j];
      float v = base + w1row[j] + b1[m * HH + j];
      h[k] = v; s += v; s2 += v * v;
    }
    r1[t] = s; r2[t] = s2;
    __syncthreads();
    for (int o = 128; o > 0; o >>= 1) {
      if (t < o) { r1[t] += r1[t + o]; r2[t] += r2[t + o]; }
      __syncthreads();
    }
    float mu = r1[0] * (1.f / HH);
    float var = r2[0] * (1.f / HH) - mu * mu;
    float rstd = rsqrtf(var + 1e-5f);
    float* ao = act + (size_t)m * HH * CC;
#pragma unroll
    for (int k = 0; k < 8; ++k) {
      int j = t + k * 256;
      float v = (h[k] - mu) * rstd * lng[m * HH + j] + lnb[m * HH + j];
      v = v > 0.f ? v : 0.2f * v;
      ao[(size_t)j * CC + c] = v;   // [m][j][c] for uniform scalar gemm reads
    }
  }
}

// L3: sequential copy + deterministic class-sum.
// Block (s, dg, m): waves 0-2 stream-copy contiguous row ranges (feat->out);
// wave 3 re-reads the same rows in order (L2-hot, paced via volatile LDS
// progress) and accumulates per-class sums into LDS. No atomics on data;
// single-writer accumulator => bit-deterministic. Pacing affects timing only.
__global__ void __launch_bounds__(256)
k_copysum(const float* __restrict__ feat, const int* __restrict__ labels,
          float* __restrict__ out, ushort_t* __restrict__ psum,
          float* __restrict__ scsum, int BN) {
  __shared__ float acc[CC][DSL];      // 51.2 KB
  __shared__ float scacc[CC];
  __shared__ int slab[CHUNK];
  __shared__ volatile int prog[3];
  int bid = blockIdx.x, t = threadIdx.x;
  int s = bid / (DG * MM), rem = bid % (DG * MM);
  int dg = rem / MM, m = rem % MM;
  int b0 = s * CHUNK;
  int nr = min(CHUNK, BB - b0);
  int w = t >> 6, lane = t & 63;
  for (int i = t; i < CC * DSL; i += 256) (&acc[0][0])[i] = 0.f;
  if (t < CC) scacc[t] = 0.f;
  if (t < 3) prog[t] = -1;
  __syncthreads();
  int d0 = dg * DSL + lane * 2;
  const float* fb = feat + ((size_t)m * BB + b0) * DD + d0;
  float* ob = out + ((size_t)m * BN + b0) * DD + d0;
  int e0 = nr / 3, e1 = (2 * nr) / 3;
  if (w < 3) {
    int rs = (w == 0) ? 0 : (w == 1 ? e0 : e1);
    int re = (w == 0) ? e0 : (w == 1 ? e1 : nr);
    int r = rs;
    for (; r + 8 <= re; r += 8) {
      f2v v[8];
#pragma unroll
      for (int k = 0; k < 8; ++k)
        v[k] = *(const f2v*)(fb + (size_t)(r + k) * DD);
#pragma unroll
      for (int k = 0; k < 8; ++k)
        *(f2v*)(ob + (size_t)(r + k) * DD) = v[k];
      if (lane == 0) prog[w] = r + 7;
    }
    for (; r < re; ++r) {
      f2v v = *(const f2v*)(fb + (size_t)r * DD);
      *(f2v*)(ob + (size_t)r * DD) = v;
      if (lane == 0) prog[w] = r;
    }
  } else {
    for (int i = lane; i < nr; i += 64) slab[i] = labels[b0 + i];
    int g = 0;
    for (; g + 8 <= nr; g += 8) {
      int ge = g + 8;
      for (;;) {  // pacing only — data correctness independent of this
        bool ok = true;
        if (g < e0) ok = ok && (prog[0] >= min(ge, e0) - 1);
        if (ge > e0 && g < e1) ok = ok && (prog[1] >= min(ge, e1) - 1);
        if (ge > e1) ok = ok && (prog[2] >= ge - 1);
        if (ok) break;
        __builtin_amdgcn_s_sleep(2);
      }
      int l[8];
      f2v v[8];
#pragma unroll
      for (int k = 0; k < 8; ++k) l[k] = slab[g + k];
#pragma unroll
      for (int k = 0; k < 8; ++k)
        v[k] = *(const f2v*)(fb + (size_t)(g + k) * DD);
      unsigned live = 0xFFu;
#pragma unroll
      for (int j = 1; j < 8; ++j) {
#pragma unroll
        for (int i2 = 0; i2 < j; ++i2) {
          if (l[i2] == l[j]) { v[i2] += v[j]; live &= ~(1u << j); break; }
        }
      }
#pragma unroll
      for (int k = 0; k < 8; ++k) {
        if (!(live & (1u << k))) continue;
        int c = l[k];
        f2v* ap = (f2v*)(&acc[c][lane * 2]);
        *ap += v[k];                       // single-writer LDS rmw
        float sv = v[k].x + v[k].y;
        for (int o2 = 32; o2 > 0; o2 >>= 1) sv += __shfl_xor(sv, o2);
        if (lane == 0) scacc[c] += sv;
      }
    }
    for (; g < nr; ++g) {                  // tail rows, one at a time
      int ow = (g < e0) ? 0 : (g < e1 ? 1 : 2);
      while (prog[ow] < g) __builtin_amdgcn_s_sleep(2);
      int c = slab[g];
      f2v v = *(const f2v*)(fb + (size_t)g * DD);
      f2v* ap = (f2v*)(&acc[c][lane * 2]);
      *ap += v;
      float sv = v.x + v.y;
      for (int o2 = 32; o2 > 0; o2 >>= 1) sv += __shfl_xor(sv, o2);
      if (lane == 0) scacc[c] += sv;
    }
  }
  __syncthreads();
  // flush acc -> psum (bf16), scacc -> scsum (f32, exact mask path)
  unsigned* pb = (unsigned*)psum
      + ((((size_t)s * MM + m) * CC) * DD + (size_t)dg * DSL) / 2;
  for (int i = t; i < CC * (DSL / 2); i += 256) {
    int c = i / (DSL / 2), col2 = i % (DSL / 2);
    pb[(size_t)c * (DD / 2) + col2] =
        pack2bf(acc[c][col2 * 2], acc[c][col2 * 2 + 1]);
  }
  if (t < CC)
    scsum[(((size_t)s * DG + dg) * MM + m) * 128 + t] = scacc[t];
}

// L4: gpart[m][dg][kc][c][d'] (bf16) = sum_{j in chunk} act[m][j][c]*W2[m][j][d]
__global__ void __launch_bounds__(256)
k_gemm(const float* __restrict__ act, const float* __restrict__ W2,
       ushort_t* __restrict__ gpart) {
  int dg = blockIdx.x, kc = blockIdx.y;
  int m = blockIdx.z >> 2, ch = blockIdx.z & 3;
  int t = threadIdx.x;
  int d = dg * DR2 + t;
  int j0 = kc * JL, c0 = ch * CH;
  float acc2[CH];
#pragma unroll
  for (int c = 0; c < CH; ++c) acc2[c] = 0.f;
  const float* ab = act + ((size_t)m * HH + j0) * CC + c0;
  const float* wb = W2 + ((size_t)m * HH + j0) * DD + d;
  for (int j = 0; j < JL; ++j) {
    float w2v = wb[(size_t)j * DD];
    const float* aj = ab + (size_t)j * CC;   // uniform -> scalar loads
#pragma unroll
    for (int c = 0; c < CH; ++c) acc2[c] = fmaf(aj[c], w2v, acc2[c]);
  }
  ushort_t* pb = gpart + ((size_t)(m * DG2 + dg) * KC + kc) * (CC * DR2)
               + (size_t)c0 * DR2 + t;
#pragma unroll
  for (int c = 0; c < CH; ++c) pb[(size_t)c * DR2] = f2bf(acc2[c]);
}

// L5: g = sum_kc gpart + b2; proto from psum stripes; mask from exact scsum;
//     blend; scatter to the gen rows of class c.
__global__ void __launch_bounds__(256)
k_final2(const ushort_t* __restrict__ gpart, const ushort_t* __restrict__ psum,
         const float* __restrict__ scsum, const int* __restrict__ counts,
         const float* __restrict__ b2, const float* __restrict__ corr,
         const int* __restrict__ gen, const int* __restrict__ off,
         float* __restrict__ out, int BN) {
  int c = blockIdx.x, m = blockIdx.y, t = threadIdx.x;
  int g = gen[c];
  if (g == 0) return;
  int d0 = t * 4, dg = d0 >> 8, dsub = d0 & 255;
  f4v a = {0.f, 0.f, 0.f, 0.f};
#pragma unroll
  for (int kc = 0; kc < KC; ++kc) {
    const ushort_t* q = &gpart[((size_t)(m * DG2 + dg) * KC + kc) * (CC * DR2)
                               + c * DR2 + dsub];
    a.x += bf2f(q[0]); a.y += bf2f(q[1]); a.z += bf2f(q[2]); a.w += bf2f(q[3]);
  }
  a += *(const f4v*)(&b2[m * DD + d0]);
  int oms[2];
  { int k = 0;
#pragma unroll
    for (int om = 0; om < MM; ++om) if (om != m) oms[k++] = om; }
  int cnt = counts[c];
  float inv = cnt > 0 ? 1.f / (float)cnt : 0.f;
  f4v pom[2];
#pragma unroll
  for (int k = 0; k < 2; ++k) {
    f4v p = {0.f, 0.f, 0.f, 0.f};
    for (int s = 0; s < SS; ++s) {
      const ushort_t* q = &psum[(((size_t)s * MM + oms[k]) * CC + c) * DD + d0];
      p.x += bf2f(q[0]); p.y += bf2f(q[1]); p.z += bf2f(q[2]); p.w += bf2f(q[3]);
    }
    p *= inv;
    pom[k] = p;
  }
  __shared__ float red[2][256];
  float p0 = 0.f, p1 = 0.f;
  for (int i = t; i < SS * DG; i += 256) {
    int s = i / DG, dgg = i % DG;
    p0 += scsum[(((size_t)s * DG + dgg) * MM + oms[0]) * 128 + c];
    p1 += scsum[(((size_t)s * DG + dgg) * MM + oms[1]) * 128 + c];
  }
  red[0][t] = p0; red[1][t] = p1;
  __syncthreads();
  for (int o = 128; o > 0; o >>= 1) {
    if (t < o) { red[0][t] += red[0][t + o]; red[1][t] += red[1][t + o]; }
    __syncthreads();
  }
#pragma unroll
  for (int k = 0; k < 2; ++k) {
    float al = corr[m * MM + oms[k]] * (red[k][0] > 0.f ? 1.f : 0.f);
    float ia = 1.f - al;
    a = a * ia + pom[k] * al;
  }
  int row0 = BB + off[c];
  for (int k = 0; k < g; ++k)
    *(f4v*)(&out[((size_t)m * BN + row0 + k) * DD + d0]) = a;
}

}  // namespace

extern "C" void kernel_launch(void* const* d_in, const int* in_sizes, int n_in,
                              void* d_out, int out_size, void* d_ws, size_t ws_size,
                              hipStream_t stream) {
  const float* features = (const float*)d_in[0];
  const float* fused    = (const float*)d_in[1];
  const int*   labels   = (const int*)d_in[2];
  const float* W1       = (const float*)d_in[3];
  const float* b1       = (const float*)d_in[4];
  const float* lng      = (const float*)d_in[5];
  const float* lnb      = (const float*)d_in[6];
  const float* W2       = (const float*)d_in[7];
  const float* b2       = (const float*)d_in[8];
  const float* corr     = (const float*)d_in[9];
  const float* dw       = (const float*)d_in[10];
  float* out = (float*)d_out;
  char*  ws  = (char*)d_ws;

  const int BN = (out_size - 1) / (MM * DD + 1);  // B + N
  const int N  = BN - BB;
  const size_t L0 = (size_t)MM * BN * DD;         // start of combined_labels

  int*      counts = (int*)(ws + WS_COUNTS);
  int*      gen    = (int*)(ws + WS_GEN);
  int*      off    = (int*)(ws + WS_OFF);
  int*      bhist  = (int*)(ws + WS_BHIST);
  float*    bpart  = (float*)(ws + WS_BPART);
  float*    scsum  = (float*)(ws + WS_SCSUM);
  float*    act    = (float*)(ws + WS_ACT);
  ushort_t* psum   = (ushort_t*)(ws + WS_PSUM);
  ushort_t* gpart  = (ushort_t*)(ws + WS_GPART);

  k_hist_base<<<NB + NBASE, 256, 0, stream>>>(labels, fused, W1, bhist, bpart,
                                              out + L0);
  k_plan_act<<<1 + CC * MM, 256, 0, stream>>>(bhist, W1, b1, lng, lnb, bpart,
                                              counts, gen, off, act,
                                              out + L0 + BB, out + L0 + BN,
                                              dw, N);
  k_copysum<<<NCPS, 256, 0, stream>>>(features, labels, out, psum, scsum, BN);
  k_gemm<<<dim3(DG2, KC, MM * CSPL), 256, 0, stream>>>(act, W2, gpart);
  k_final2<<<dim3(CC, MM), 256, 0, stream>>>(gpart, psum, scsum, counts, b2,
                                             corr, gen, off, out, BN);
}

// Round 10
// 297.572 us; speedup vs baseline: 1.4311x; 1.4311x over previous
//
#include <hip/hip_runtime.h>

namespace {

typedef float f4v __attribute__((ext_vector_type(4)));
typedef float f2v __attribute__((ext_vector_type(2)));
typedef unsigned short ushort_t;

constexpr int MM = 3;
constexpr int BB = 16384;
constexpr int DD = 1024;
constexpr int CC = 100;
constexpr int HH = 2048;             // 2*DD
constexpr int DESIRED = BB / CC;     // 163
constexpr int NB  = BB / 256;        // 64 label blocks

// copysum geometry
constexpr int SS    = 28;            // row stripes
constexpr int CHUNK = 586;           // 28*586 >= 16384 (last stripe 562)
constexpr int RU    = 16;            // row unroll (16 rows in flight)

// base matvec partition
constexpr int DBS   = 4;
constexpr int NBASE = (HH / 256) * DBS * MM;  // 96
// class-GEMM geometry (W2 read exactly once)
constexpr int KC  = 4, JL = HH / KC;    // 512 j per block
constexpr int DG2 = 4,  DR2 = 256;
constexpr int CSPL = 4, CH = CC / CSPL; // 4x25 class split

// ws byte offsets (total 21.3 MB < proven 23.66 MB)
constexpr size_t WS_COUNTS = 0;          // 128 int
constexpr size_t WS_GEN    = 512;        // 128 int
constexpr size_t WS_OFF    = 1024;       // 128 int
constexpr size_t WS_BHIST  = 4096;       // NB*128 int (32 KB)
constexpr size_t WS_BPART  = 36864;      // DBS*MM*HH f32 (96 KB)
constexpr size_t WS_SCPART = 135168;     // SS*MM*2*128 f32 (86 KB)
constexpr size_t WS_ACT    = 221184;     // MM*HH*CC f32 (2.4 MB)
constexpr size_t WS_GPART  = 2678784;    // MM*DG2*KC*CC*DR2 bf16 (2.4 MB)
constexpr size_t WS_PSUM   = 5136384;    // SS*MM*CC*DD bf16 (17.2 MB)

__device__ __forceinline__ float bits2f(unsigned u) {
  union { unsigned i; float f; } x; x.i = u; return x.f;
}
__device__ __forceinline__ ushort_t f2bf(float f) {
  union { float f; unsigned i; } x; x.f = f;
  unsigned r = x.i + 0x7FFFu + ((x.i >> 16) & 1u);
  return (ushort_t)(r >> 16);
}
__device__ __forceinline__ unsigned pack2bf(float a, float b) {
  return (unsigned)f2bf(a) | ((unsigned)f2bf(b) << 16);
}
__device__ __forceinline__ float bf2f(ushort_t u) {
  return bits2f(((unsigned)u) << 16);
}

// L1: per-block label histogram + head labels || base matvec partials.
__global__ void __launch_bounds__(256)
k_hist_base(const int* __restrict__ labels, const float* __restrict__ fused,
            const float* __restrict__ W1, int* __restrict__ bhist,
            float* __restrict__ bpart, float* __restrict__ out_lab) {
  int bid = blockIdx.x, t = threadIdx.x;
  if (bid < NB) {
    __shared__ int h[128];
    if (t < 128) h[t] = 0;
    __syncthreads();
    int b = bid * 256 + t;
    int l = labels[b];
    atomicAdd(&h[l], 1);
    out_lab[b] = (float)l;
    __syncthreads();
    if (t < 128) bhist[bid * 128 + t] = h[t];
  } else {
    int b3 = bid - NB;
    int jb = b3 % (HH / 256), db = (b3 / (HH / 256)) % DBS,
        m = b3 / ((HH / 256) * DBS);
    int j = jb * 256 + t;
    const float* w = W1 + ((size_t)m * (DD + CC)) * HH + j;
    float acc = 0.f;
    int dlo = db * (DD / DBS);
#pragma unroll 8
    for (int d = dlo; d < dlo + DD / DBS; ++d)
      acc = fmaf(fused[d], w[(size_t)d * HH], acc);
    bpart[((size_t)db * MM + m) * HH + j] = acc;
  }
}

// L2: block 0 = plan (counts/gen/off, tail labels, loss);
//     blocks 1..300 = LN-activation -> act[m][j][c].
__global__ void __launch_bounds__(256)
k_plan_act(const int* __restrict__ bhist, const float* __restrict__ W1,
           const float* __restrict__ b1, const float* __restrict__ lng,
           const float* __restrict__ lnb, const float* __restrict__ bpart,
           int* __restrict__ counts, int* __restrict__ gen,
           int* __restrict__ off, float* __restrict__ act,
           float* __restrict__ out_lab_tail, float* __restrict__ out_loss,
           const float* __restrict__ dw, int N) {
  __shared__ float r1[256], r2[256];
  int bid = blockIdx.x, t = threadIdx.x;
  if (bid == 0) {
    __shared__ int s[128], soff[CC + 1];
    int run = 0;
    if (t < 128) {
      for (int blk = 0; blk < NB; ++blk) run += bhist[blk * 128 + t];
      counts[t] = run;
    }
    int cnt = (t < CC) ? run : 0;
    int g = (t < CC && cnt > 0) ? max(DESIRED - cnt, 0) : 0;
    if (t < 128) s[t] = g;
    __syncthreads();
    for (int o = 1; o < 128; o <<= 1) {
      int v = (t < 128 && t >= o) ? s[t - o] : 0;
      __syncthreads();
      if (t < 128) s[t] += v;
      __syncthreads();
    }
    if (t < CC) {
      int excl = s[t] - g;
      gen[t] = g;
      off[t] = excl;
      soff[t] = excl;
    }
    if (t == 0) {
      soff[CC] = N;
      *out_loss = (N > 0) ? 0.1f * dw[0] : 0.0f;
    }
    __syncthreads();
    for (int i = t; i < N; i += 256) {
      int lo = 0, hi = CC;
      while (hi - lo > 1) {
        int mid = (lo + hi) >> 1;
        if (soff[mid] <= i) lo = mid; else hi = mid;
      }
      out_lab_tail[i] = (float)lo;
    }
  } else {
    int b2 = bid - 1;
    int c = b2 % CC, m = b2 / CC;
    const float* w1row = W1 + ((size_t)m * (DD + CC) + DD + c) * HH;
    float h[8];
    float s = 0.f, s2 = 0.f;
#pragma unroll
    for (int k = 0; k < 8; ++k) {
      int j = t + k * 256;
      float base = bpart[(size_t)(0 * MM + m) * HH + j]
                 + bpart[(size_t)(1 * MM + m) * HH + j]
                 + bpart[(size_t)(2 * MM + m) * HH + j]
                 + bpart[(size_t)(3 * MM + m) * HH + j];
      float v = base + w1row[j] + b1[m * HH + j];
      h[k] = v; s += v; s2 += v * v;
    }
    r1[t] = s; r2[t] = s2;
    __syncthreads();
    for (int o = 128; o > 0; o >>= 1) {
      if (t < o) { r1[t] += r1[t + o]; r2[t] += r2[t + o]; }
      __syncthreads();
    }
    float mu = r1[0] * (1.f / HH);
    float var = r2[0] * (1.f / HH) - mu * mu;
    float rstd = rsqrtf(var + 1e-5f);
    float* ao = act + (size_t)m * HH * CC;
#pragma unroll
    for (int k = 0; k < 8; ++k) {
      int j = t + k * 256;
      float v = (h[k] - mu) * rstd * lng[m * HH + j] + lnb[m * HH + j];
      v = v > 0.f ? v : 0.2f * v;
      ao[(size_t)j * CC + c] = v;   // [m][j][c] for uniform scalar gemm reads
    }
  }
}

// L3: sequential full-row copy + deterministic class-sum in packed-bf16 LDS.
// Block (h, m, s), 512 threads; thread t owns cols (2t, 2t+1).
// h=0: reads full rows sequentially, writes the copy, updates cols 0..511.
// h=1: waves 4-7 read cols 512..1023 (L2/L3-hot behind h=0) and update them.
// No atomics, fixed order => bit-deterministic. Flush psum bf16 + scpart f32.
__global__ void __launch_bounds__(512)
k_copysum(const float* __restrict__ feat, const int* __restrict__ labels,
          float* __restrict__ out, ushort_t* __restrict__ psum,
          float* __restrict__ scpart, int BN) {
  __shared__ unsigned accp[CC][256];   // 100 KB: packed 2xbf16 per col pair
  __shared__ int slab[CHUNK];
  int h = blockIdx.x, m = blockIdx.y, s = blockIdx.z;
  int t = threadIdx.x;
  int b0 = s * CHUNK, nr = min(CHUNK, BB - b0);
  for (int i = t; i < CC * 256; i += 512) (&accp[0][0])[i] = 0u;
  for (int i = t; i < nr; i += 512) slab[i] = labels[b0 + i];
  __syncthreads();
  bool upd = (t >> 8) == h;          // wave-uniform
  int j = t & 255;
  const float* fb = feat + ((size_t)m * BB + b0) * DD + 2 * t;
  float* ob = out + ((size_t)m * BN + b0) * DD + 2 * t;
  if (h == 0 || upd) {
    int r = 0;
    for (; r + RU <= nr; r += RU) {
      f2v v[RU];
#pragma unroll
      for (int k = 0; k < RU; ++k)
        v[k] = *(const f2v*)(fb + (size_t)(r + k) * DD);
      if (h == 0) {
#pragma unroll
        for (int k = 0; k < RU; ++k)
          *(f2v*)(ob + (size_t)(r + k) * DD) = v[k];
      }
      if (upd) {
#pragma unroll
        for (int k = 0; k < RU; ++k) {
          int c = slab[r + k];
          unsigned u = accp[c][j];
          float lo = bits2f(u << 16) + v[k].x;
          float hi = bits2f(u & 0xFFFF0000u) + v[k].y;
          accp[c][j] = pack2bf(lo, hi);
        }
      }
    }
    for (; r < nr; ++r) {
      f2v v = *(const f2v*)(fb + (size_t)r * DD);
      if (h == 0) *(f2v*)(ob + (size_t)r * DD) = v;
      if (upd) {
        int c = slab[r];
        unsigned u = accp[c][j];
        float lo = bits2f(u << 16) + v.x;
        float hi = bits2f(u & 0xFFFF0000u) + v.y;
        accp[c][j] = pack2bf(lo, hi);
      }
    }
  }
  __syncthreads();
  // flush: psum[(s*MM+m)*CC + c][col] bf16, this block's half-cols
  ushort_t* pb = psum + ((size_t)(s * MM + m) * CC) * DD + h * 512;
  for (int i = t; i < CC * 256; i += 512) {
    int c = i >> 8, jj = i & 255;
    *(unsigned*)(pb + (size_t)c * DD + 2 * jj) = accp[c][jj];
  }
  // scpart: per-class f32 sum of this block's acc (fixed order, deterministic)
  if (t < CC) {
    float ssum = 0.f;
    for (int jj = 0; jj < 256; ++jj) {
      unsigned u = accp[t][jj];
      ssum += bits2f(u << 16) + bits2f(u & 0xFFFF0000u);
    }
    scpart[(size_t)((s * MM + m) * 2 + h) * 128 + t] = ssum;
  }
}

// L4: gpart[m][dg][kc][c][d'] (bf16) = sum_{j in chunk} act[m][j][c]*W2[m][j][d]
__global__ void __launch_bounds__(256)
k_gemm(const float* __restrict__ act, const float* __restrict__ W2,
       ushort_t* __restrict__ gpart) {
  int dg = blockIdx.x, kc = blockIdx.y;
  int m = blockIdx.z >> 2, ch = blockIdx.z & 3;
  int t = threadIdx.x;
  int d = dg * DR2 + t;
  int j0 = kc * JL, c0 = ch * CH;
  float acc2[CH];
#pragma unroll
  for (int c = 0; c < CH; ++c) acc2[c] = 0.f;
  const float* ab = act + ((size_t)m * HH + j0) * CC + c0;
  const float* wb = W2 + ((size_t)m * HH + j0) * DD + d;
  for (int j = 0; j < JL; ++j) {
    float w2v = wb[(size_t)j * DD];
    const float* aj = ab + (size_t)j * CC;   // uniform -> scalar loads
#pragma unroll
    for (int c = 0; c < CH; ++c) acc2[c] = fmaf(aj[c], w2v, acc2[c]);
  }
  ushort_t* pb = gpart + ((size_t)(m * DG2 + dg) * KC + kc) * (CC * DR2)
               + (size_t)c0 * DR2 + t;
#pragma unroll
  for (int c = 0; c < CH; ++c) pb[(size_t)c * DR2] = f2bf(acc2[c]);
}

// L5: g = sum_kc gpart + b2; proto = f32-sum of psum stripes / cnt;
//     mask from scpart (fixed-tree reduce); blend; scatter to gen rows.
__global__ void __launch_bounds__(256)
k_final2(const ushort_t* __restrict__ gpart, const ushort_t* __restrict__ psum,
         const float* __restrict__ scpart, const int* __restrict__ counts,
         const float* __restrict__ b2, const float* __restrict__ corr,
         const int* __restrict__ gen, const int* __restrict__ off,
         float* __restrict__ out, int BN) {
  int c = blockIdx.x, m = blockIdx.y, t = threadIdx.x;
  int g = gen[c];
  if (g == 0) return;
  int d0 = t * 4, dg = d0 >> 8, dsub = d0 & 255;
  f4v a = {0.f, 0.f, 0.f, 0.f};
#pragma unroll
  for (int kc = 0; kc < KC; ++kc) {
    const ushort_t* q = &gpart[((size_t)(m * DG2 + dg) * KC + kc) * (CC * DR2)
                               + c * DR2 + dsub];
    a.x += bf2f(q[0]); a.y += bf2f(q[1]); a.z += bf2f(q[2]); a.w += bf2f(q[3]);
  }
  a += *(const f4v*)(&b2[m * DD + d0]);
  int oms[2];
  { int k = 0;
#pragma unroll
    for (int om = 0; om < MM; ++om) if (om != m) oms[k++] = om; }
  int cnt = counts[c];
  float inv = cnt > 0 ? 1.f / (float)cnt : 0.f;
  f4v pom[2];
#pragma unroll
  for (int k = 0; k < 2; ++k) {
    f4v p = {0.f, 0.f, 0.f, 0.f};
    for (int s = 0; s < SS; ++s) {
      const ushort_t* q = &psum[((size_t)(s * MM + oms[k]) * CC + c) * DD + d0];
      p.x += bf2f(q[0]); p.y += bf2f(q[1]); p.z += bf2f(q[2]); p.w += bf2f(q[3]);
    }
    p *= inv;
    pom[k] = p;
  }
  __shared__ float red[2][256];
  float p0 = 0.f, p1 = 0.f;
  for (int i = t; i < SS * 2; i += 256) {
    int s = i >> 1, hh = i & 1;
    p0 += scpart[(size_t)((s * MM + oms[0]) * 2 + hh) * 128 + c];
    p1 += scpart[(size_t)((s * MM + oms[1]) * 2 + hh) * 128 + c];
  }
  red[0][t] = p0; red[1][t] = p1;
  __syncthreads();
  for (int o = 128; o > 0; o >>= 1) {
    if (t < o) { red[0][t] += red[0][t + o]; red[1][t] += red[1][t + o]; }
    __syncthreads();
  }
#pragma unroll
  for (int k = 0; k < 2; ++k) {
    float al = corr[m * MM + oms[k]] * (red[k][0] > 0.f ? 1.f : 0.f);
    float ia = 1.f - al;
    a = a * ia + pom[k] * al;
  }
  int row0 = BB + off[c];
  for (int k = 0; k < g; ++k)
    *(f4v*)(&out[((size_t)m * BN + row0 + k) * DD + d0]) = a;
}

}  // namespace

extern "C" void kernel_launch(void* const* d_in, const int* in_sizes, int n_in,
                              void* d_out, int out_size, void* d_ws, size_t ws_size,
                              hipStream_t stream) {
  const float* features = (const float*)d_in[0];
  const float* fused    = (const float*)d_in[1];
  const int*   labels   = (const int*)d_in[2];
  const float* W1       = (const float*)d_in[3];
  const float* b1       = (const float*)d_in[4];
  const float* lng      = (const float*)d_in[5];
  const float* lnb      = (const float*)d_in[6];
  const float* W2       = (const float*)d_in[7];
  const float* b2       = (const float*)d_in[8];
  const float* corr     = (const float*)d_in[9];
  const float* dw       = (const float*)d_in[10];
  float* out = (float*)d_out;
  char*  ws  = (char*)d_ws;

  const int BN = (out_size - 1) / (MM * DD + 1);  // B + N
  const int N  = BN - BB;
  const size_t L0 = (size_t)MM * BN * DD;         // start of combined_labels

  int*      counts = (int*)(ws + WS_COUNTS);
  int*      gen    = (int*)(ws + WS_GEN);
  int*      off    = (int*)(ws + WS_OFF);
  int*      bhist  = (int*)(ws + WS_BHIST);
  float*    bpart  = (float*)(ws + WS_BPART);
  float*    scpart = (float*)(ws + WS_SCPART);
  float*    act    = (float*)(ws + WS_ACT);
  ushort_t* gpart  = (ushort_t*)(ws + WS_GPART);
  ushort_t* psum   = (ushort_t*)(ws + WS_PSUM);

  k_hist_base<<<NB + NBASE, 256, 0, stream>>>(labels, fused, W1, bhist, bpart,
                                              out + L0);
  k_plan_act<<<1 + CC * MM, 256, 0, stream>>>(bhist, W1, b1, lng, lnb, bpart,
                                              counts, gen, off, act,
                                              out + L0 + BB, out + L0 + BN,
                                              dw, N);
  k_copysum<<<dim3(2, MM, SS), 512, 0, stream>>>(features, labels, out, psum,
                                                 scpart, BN);
  k_gemm<<<dim3(DG2, KC, MM * CSPL), 256, 0, stream>>>(act, W2, gpart);
  k_final2<<<dim3(CC, MM), 256, 0, stream>>>(gpart, psum, scpart, counts, b2,
                                             corr, gen, off, out, BN);
}